// Round 20
// baseline (450.003 us; speedup 1.0000x reference)
//
#include <hip/hip_runtime.h>
#include <hip/hip_bf16.h>

typedef __bf16 bf16;
typedef __attribute__((ext_vector_type(8))) __bf16 bf16x8;
typedef __attribute__((ext_vector_type(4))) float f32x4;

#define GLOAD_LDS16(g, l)                                                        \
    __builtin_amdgcn_global_load_lds(                                            \
        (const __attribute__((address_space(1))) void*)(g),                      \
        (__attribute__((address_space(3))) void*)(l), 16, 0, 0)

#define WAITV(n) asm volatile("s_waitcnt vmcnt(" #n ")" ::: "memory")
#define LGKM0()  asm volatile("s_waitcnt lgkmcnt(0)" ::: "memory")
#define BAR()    __builtin_amdgcn_s_barrier()
#define SCHEDB() __builtin_amdgcn_sched_barrier(0)

__device__ __forceinline__ void cvt16(const float* __restrict__ p, bf16* __restrict__ q) {
    f32x4 a = *(const f32x4*)p;
    f32x4 b = *(const f32x4*)(p + 4);
    f32x4 c = *(const f32x4*)(p + 8);
    f32x4 d = *(const f32x4*)(p + 12);
    bf16x8 h0, h1;
#pragma unroll
    for (int j = 0; j < 4; ++j) {
        h0[j] = (bf16)a[j]; h0[4 + j] = (bf16)b[j];
        h1[j] = (bf16)c[j]; h1[4 + j] = (bf16)d[j];
    }
    *(bf16x8*)q = h0;
    *(bf16x8*)(q + 8) = h1;
}

// ---------------- fp32 -> bf16 conversion (single src) ----------------
__global__ __launch_bounds__(256) void cvt_f32_bf16(
    const float* __restrict__ src, bf16* __restrict__ dst, int n16)
{
    int idx = blockIdx.x * 256 + threadIdx.x;
    const int stride = gridDim.x * 256;
    for (int i = idx; i < n16; i += stride)
        cvt16(src + (size_t)i * 16, dst + (size_t)i * 16);
}

// ---------------- fused two-segment conversion (x + w_qkv, one launch) ----------------
__global__ __launch_bounds__(256) void cvt2_f32_bf16(
    const float* __restrict__ s1, bf16* __restrict__ d1, int n1,
    const float* __restrict__ s2, bf16* __restrict__ d2, int n2)
{
    int idx = blockIdx.x * 256 + threadIdx.x;
    const int stride = gridDim.x * 256;
    const int ntot = n1 + n2;
    for (int i = idx; i < ntot; i += stride) {
        if (i < n1) cvt16(s1 + (size_t)i * 16, d1 + (size_t)i * 16);
        else {
            const int j = i - n1;
            cvt16(s2 + (size_t)j * 16, d2 + (size_t)j * 16);
        }
    }
}

// ---- r11-verified single-phase 3-deep GEMM: C[M][N] = A[M][K]*B[N][K]^T + bias ----
// BM=128, BN=256, BK=64, 8 waves (2M x 4N -> per-wave 64x64). Measured: 44% MfmaUtil,
// 0 bank conflicts, 246 MB fetch (locality window). Per K-tile: {16 ds_read_b128 ||
// stage t+2 (6 gloads)} -> 32 MFMA -> WAITV(6) -> bar. 3 LDS bufs x 48KB = 144KB.
// Swizzle (r6 HW-verified): phys 16B-slot s of row r holds chunk s^(r&7).
// Block map (nbx%16==0): 256-block window = 16 bx x 16 by; XCD owns 2 bx x 16 by.
template <int OUT_BF16>
__global__ __launch_bounds__(512, 2) void gemm_sp(
    const bf16* __restrict__ A, const bf16* __restrict__ B,
    const float* __restrict__ bias, void* __restrict__ Cout,
    int K, int ldc, int nbx)
{
    constexpr int ASZ = 128 * 64;
    constexpr int BUF = ASZ + 256 * 64;        // 24576 elems = 48KB
    __shared__ bf16 lds[3 * BUF];

    int bx, by;
    if ((nbx & 15) == 0) {
        const int r = (int)blockIdx.x & 255;
        const int slot = r >> 3;
        bx = ((int)blockIdx.x >> 8) * 16 + (r & 7) * 2 + (slot >> 4);
        by = slot & 15;
    } else {
        const int cpx = gridDim.x >> 3;
        const int swz = ((int)blockIdx.x & 7) * cpx + ((int)blockIdx.x >> 3);
        bx = swz % nbx; by = swz / nbx;
    }
    const int brow = by * 128, bcol = bx * 256;

    const int tid  = threadIdx.x;
    const int wv   = tid >> 6, lane = tid & 63;
    const int lo   = lane & 15, hi = lane >> 4;
    const int wrp  = wv >> 2, wcp = wv & 3;

    const int srow = lane >> 3;
    const int scol = ((lane & 7) ^ (lane >> 3)) * 8;

    f32x4 acc[4][4];
#pragma unroll
    for (int m = 0; m < 4; ++m)
#pragma unroll
        for (int n = 0; n < 4; ++n)
            acc[m][n] = (f32x4){0.f, 0.f, 0.f, 0.f};

    auto STAGE = [&](int t) {
        const int k0 = t * 64;
        bf16* lb = &lds[(t % 3) * BUF];
#pragma unroll
        for (int j = 0; j < 2; ++j) {
            const int c = wv * 2 + j;
            GLOAD_LDS16(A + (size_t)(brow + c * 8 + srow) * K + k0 + scol, lb + c * 512);
        }
#pragma unroll
        for (int j = 0; j < 4; ++j) {
            const int c = wv * 4 + j;
            GLOAD_LDS16(B + (size_t)(bcol + c * 8 + srow) * K + k0 + scol, lb + ASZ + c * 512);
        }
    };

    const int nt = K / 64;
    STAGE(0); STAGE(1);
    WAITV(6); BAR(); SCHEDB();

    for (int t = 0; t < nt; ++t) {
        const bf16* lb = &lds[(t % 3) * BUF];
        bf16x8 af[4][2], bfr[4][2];
#pragma unroll
        for (int m = 0; m < 4; ++m) {
            const int ru = wrp * 64 + m * 16 + lo;
#pragma unroll
            for (int kk = 0; kk < 2; ++kk)
                af[m][kk] = *(const bf16x8*)&lb[ru * 64 + (((kk * 4 + hi) ^ (lo & 7)) * 8)];
        }
#pragma unroll
        for (int n = 0; n < 4; ++n) {
            const int rb = wcp * 64 + n * 16 + lo;
#pragma unroll
            for (int kk = 0; kk < 2; ++kk)
                bfr[n][kk] = *(const bf16x8*)&lb[ASZ + rb * 64 + (((kk * 4 + hi) ^ (lo & 7)) * 8)];
        }

        if (t + 2 < nt) STAGE(t + 2);

        __builtin_amdgcn_s_setprio(1);
#pragma unroll
        for (int m = 0; m < 4; ++m)
#pragma unroll
            for (int n = 0; n < 4; ++n)
#pragma unroll
                for (int kk = 0; kk < 2; ++kk)
                    acc[m][n] = __builtin_amdgcn_mfma_f32_16x16x32_bf16(af[m][kk], bfr[n][kk], acc[m][n], 0, 0, 0);
        __builtin_amdgcn_s_setprio(0);

        if (t + 2 < nt)      WAITV(6);
        else if (t + 1 < nt) WAITV(0);
        if (t + 1 < nt) { BAR(); SCHEDB(); }
    }

#pragma unroll
    for (int m = 0; m < 4; ++m) {
        const int row = brow + wrp * 64 + m * 16 + hi * 4;
#pragma unroll
        for (int n = 0; n < 4; ++n) {
            const int col = bcol + wcp * 64 + n * 16 + lo;
            const float bv = bias[col];
#pragma unroll
            for (int r = 0; r < 4; ++r) {
                const float v = acc[m][n][r] + bv;
                if (OUT_BF16)
                    ((bf16*)Cout)[(size_t)(row + r) * ldc + col] = (bf16)v;
                else
                    ((float*)Cout)[(size_t)(row + r) * ldc + col] = v;
            }
        }
    }
}

// ---- MFMA flash attention + T14 async-STAGE (r17/r19-verified) + balanced qi pairing ----
// 512 blocks x 512 thr (8 waves); h = bid&31. qi map pairs heavy+light on each CU under
// round-robin placement (CU c hosts blocks c, c+256): bid<256 -> qi=15-(bid>>5) (heavy),
// bid>=256 -> qi=(bid-256)>>5 (light); per-CU tile sum = 34 const (was 48..20). Bijective;
// neutral if placement differs. All else byte-identical to the r19 verified kernel.
__global__ __launch_bounds__(512) void attn_mfma(
    const bf16* __restrict__ qkv, bf16* __restrict__ attn_out)
{
    const int S = 2048, QKV = 12288, D = 4096, HD = 128;
    const int bid = blockIdx.x;
    const int h   = bid & 31;
    const int qi  = (bid < 256) ? (15 - (bid >> 5)) : ((bid - 256) >> 5);
    const int q0  = qi * 128;
    const int tid = threadIdx.x;
    const int w    = tid >> 6, lane = tid & 63;
    const int lo   = lane & 15, hi = lane >> 4;
    const int qbase = q0 + w * 16;

    __shared__ bf16 Ks[64 * 128];
    __shared__ bf16 Vs[128 * 72];
    __shared__ bf16 Ps[8 * 16 * 72];

    const float scale = 0.08838834764831845f;
    const float slope = exp2f(-0.25f * (float)(h + 1));

    bf16x8 qfrag[4];
#pragma unroll
    for (int ds = 0; ds < 4; ++ds)
        qfrag[ds] = *(const bf16x8*)(qkv + (size_t)(qbase + lo) * QKV + h * HD + ds * 32 + hi * 8);

    f32x4 o[8];
#pragma unroll
    for (int dt = 0; dt < 8; ++dt) o[dt] = (f32x4){0.f, 0.f, 0.f, 0.f};
    float mrow[4] = {-1e30f, -1e30f, -1e30f, -1e30f};
    float lrow[4] = {0.f, 0.f, 0.f, 0.f};

    const int krow = tid >> 3;        // K: kv row 0..63
    const int kch  = tid & 7;         // K: 16-elem d-chunk
    const int vp2  = tid & 63;        // V: d-pair (d = 2*vp2)
    const int voct = tid >> 6;        // V: kv octet 0..7

    // T14 prefetch state (+16 VGPR)
    bf16x8 kpre0, kpre1;
    unsigned vpre[8];
    auto ISSUE = [&](int t) {
        const int kv0 = t * 64;
        const bf16* kp = qkv + (size_t)(kv0 + krow) * QKV + D + h * HD + kch * 16;
        kpre0 = *(const bf16x8*)kp;
        kpre1 = *(const bf16x8*)(kp + 8);
        const bf16* vp = qkv + (size_t)(kv0 + voct * 8) * QKV + 2 * D + h * HD + 2 * vp2;
#pragma unroll
        for (int j = 0; j < 8; ++j)
            vpre[j] = *(const unsigned*)(vp + (size_t)j * QKV);
    };

    const int ntile = (q0 + 128) / 64;
    ISSUE(0);
    for (int t = 0; t < ntile; ++t) {
        const int kv0 = t * 64;
        // ---- WRITE staged regs to LDS ----
        {
            const int kb  = krow * 128 + kch * 16;
            const int swzk = (krow & 7) << 3;
            *(bf16x8*)&Ks[kb ^ swzk]       = kpre0;
            *(bf16x8*)&Ks[(kb + 8) ^ swzk] = kpre1;
            bf16x8 r0, r1;
#pragma unroll
            for (int j = 0; j < 8; ++j) {
                unsigned short us0 = (unsigned short)(vpre[j] & 0xffff);
                unsigned short us1 = (unsigned short)(vpre[j] >> 16);
                r0[j] = *(const bf16*)&us0;
                r1[j] = *(const bf16*)&us1;
            }
            *(bf16x8*)&Vs[(2 * vp2) * 72 + voct * 8]     = r0;
            *(bf16x8*)&Vs[(2 * vp2 + 1) * 72 + voct * 8] = r1;
        }
        LGKM0(); BAR(); SCHEDB();            // barrier A: staged tile visible

        if (t + 1 < ntile) ISSUE(t + 1);     // HBM loads in flight under compute

        if (kv0 <= qbase + 15) {
            f32x4 c[4];
#pragma unroll
            for (int j = 0; j < 4; ++j) c[j] = (f32x4){0.f, 0.f, 0.f, 0.f};
            __builtin_amdgcn_s_setprio(1);
#pragma unroll
            for (int ds = 0; ds < 4; ++ds) {
#pragma unroll
                for (int j = 0; j < 4; ++j) {
                    const int r = j * 16 + lo;
                    bf16x8 b = *(const bf16x8*)&Ks[(r * 128 + ds * 32 + hi * 8) ^ ((r & 7) << 3)];
                    c[j] = __builtin_amdgcn_mfma_f32_16x16x32_bf16(qfrag[ds], b, c[j], 0, 0, 0);
                }
            }
            __builtin_amdgcn_s_setprio(0);
#pragma unroll
            for (int r = 0; r < 4; ++r) {
                const int q = qbase + hi * 4 + r;
                float s[4];
#pragma unroll
                for (int j = 0; j < 4; ++j) {
                    const int ki = kv0 + j * 16 + lo;
                    s[j] = c[j][r] * scale + slope * (float)(ki - (S - 1));
                    if (ki > q) s[j] = -1e30f;
                }
                float tm = fmaxf(fmaxf(s[0], s[1]), fmaxf(s[2], s[3]));
                tm = fmaxf(tm, __shfl_xor(tm, 1));
                tm = fmaxf(tm, __shfl_xor(tm, 2));
                tm = fmaxf(tm, __shfl_xor(tm, 4));
                tm = fmaxf(tm, __shfl_xor(tm, 8));
                const float mnew = fmaxf(mrow[r], tm);
                const float cr = __expf(mrow[r] - mnew);
                float p[4], ps = 0.f;
#pragma unroll
                for (int j = 0; j < 4; ++j) { p[j] = __expf(s[j] - mnew); ps += p[j]; }
                ps += __shfl_xor(ps, 1);
                ps += __shfl_xor(ps, 2);
                ps += __shfl_xor(ps, 4);
                ps += __shfl_xor(ps, 8);
                lrow[r] = lrow[r] * cr + ps;
                mrow[r] = mnew;
#pragma unroll
                for (int dt = 0; dt < 8; ++dt) o[dt][r] *= cr;
#pragma unroll
                for (int j = 0; j < 4; ++j)
                    Ps[w * 1152 + (hi * 4 + r) * 72 + j * 16 + lo] = (bf16)p[j];
            }
            bf16x8 pa0 = *(const bf16x8*)&Ps[w * 1152 + lo * 72 + hi * 8];
            bf16x8 pa1 = *(const bf16x8*)&Ps[w * 1152 + lo * 72 + 32 + hi * 8];
            __builtin_amdgcn_s_setprio(1);
#pragma unroll
            for (int dt = 0; dt < 8; ++dt) {
                bf16x8 bv0 = *(const bf16x8*)&Vs[(dt * 16 + lo) * 72 + hi * 8];
                bf16x8 bv1 = *(const bf16x8*)&Vs[(dt * 16 + lo) * 72 + 32 + hi * 8];
                o[dt] = __builtin_amdgcn_mfma_f32_16x16x32_bf16(pa0, bv0, o[dt], 0, 0, 0);
                o[dt] = __builtin_amdgcn_mfma_f32_16x16x32_bf16(pa1, bv1, o[dt], 0, 0, 0);
            }
            __builtin_amdgcn_s_setprio(0);
        }
        SCHEDB(); BAR(); SCHEDB();           // barrier B: all reads done before next WRITE
    }

#pragma unroll
    for (int r = 0; r < 4; ++r) {
        const float inv = 1.0f / lrow[r];
        const int q = qbase + hi * 4 + r;
        bf16* op = attn_out + (size_t)q * D + h * HD;
#pragma unroll
        for (int dt = 0; dt < 8; ++dt)
            op[dt * 16 + lo] = (bf16)(o[dt][r] * inv);
    }
}

extern "C" void kernel_launch(void* const* d_in, const int* in_sizes, int n_in,
                              void* d_out, int out_size, void* d_ws, size_t ws_size,
                              hipStream_t stream) {
    const int S = 2048, D = 4096, QKV = 12288;
    const int NH = 6144;
    const float* x     = (const float*)d_in[0];
    const float* w_qkv = (const float*)d_in[1];
    const float* b_qkv = (const float*)d_in[2];
    const float* w_out = (const float*)d_in[3];
    const float* b_out = (const float*)d_in[4];
    float* out = (float*)d_out;

    char* ws = (char*)d_ws;
    const size_t need_full = (size_t)S * D * 2 + (size_t)QKV * D * 2 + (size_t)S * QKV * 2;

    if (ws_size >= need_full) {
        bf16* xb    = (bf16*)ws;                                    // [2048][4096]
        bf16* attnb = xb;                                           // reuse after xb dead
        bf16* wqb   = (bf16*)(ws + (size_t)S * D * 2);              // [12288][4096]
        bf16* wob   = wqb;                                          // reuse after wqb dead
        bf16* qkvb  = (bf16*)(ws + (size_t)S * D * 2 + (size_t)QKV * D * 2);  // [2048][12288]

        cvt2_f32_bf16<<<3584, 256, 0, stream>>>(x, xb, S * D / 16, w_qkv, wqb, QKV * D / 16);
        gemm_sp<1><<<(QKV / 256) * (S / 128), 512, 0, stream>>>(xb, wqb, b_qkv, qkvb, D, QKV, QKV / 256);
        attn_mfma<<<512, 512, 0, stream>>>(qkvb, attnb);
        cvt_f32_bf16<<<2048, 256, 0, stream>>>(w_out, wob, D * D / 16);
        gemm_sp<0><<<(D / 256) * (S / 128), 512, 0, stream>>>(attnb, wob, b_out, out, D, D, D / 256);
    } else {
        bf16* xb    = (bf16*)ws;
        bf16* attnb = xb;
        bf16* wb    = (bf16*)(ws + (size_t)S * D * 2);              // [6144][4096]
        bf16* wob   = wb;
        bf16* qkvb  = (bf16*)(ws + (size_t)S * D * 2 + (size_t)NH * D * 2);

        cvt2_f32_bf16<<<3584, 256, 0, stream>>>(x, xb, S * D / 16, w_qkv, wb, NH * D / 16);
        gemm_sp<1><<<(NH / 256) * (S / 128), 512, 0, stream>>>(xb, wb, b_qkv, qkvb, D, QKV, NH / 256);
        cvt_f32_bf16<<<2048, 256, 0, stream>>>(w_qkv + (size_t)NH * D, wb, NH * D / 16);
        gemm_sp<1><<<(NH / 256) * (S / 128), 512, 0, stream>>>(xb, wb, b_qkv + NH, qkvb + NH, D, QKV, NH / 256);
        attn_mfma<<<512, 512, 0, stream>>>(qkvb, attnb);
        cvt_f32_bf16<<<2048, 256, 0, stream>>>(w_out, wob, D * D / 16);
        gemm_sp<0><<<(D / 256) * (S / 128), 512, 0, stream>>>(attnb, wob, b_out, out, D, D, D / 256);
    }
}

// Round 21
// 425.559 us; speedup vs baseline: 1.0574x; 1.0574x over previous
//
#include <hip/hip_runtime.h>
#include <hip/hip_bf16.h>

typedef __bf16 bf16;
typedef __attribute__((ext_vector_type(8))) __bf16 bf16x8;
typedef __attribute__((ext_vector_type(4))) float f32x4;

#define GLOAD_LDS16(g, l)                                                        \
    __builtin_amdgcn_global_load_lds(                                            \
        (const __attribute__((address_space(1))) void*)(g),                      \
        (__attribute__((address_space(3))) void*)(l), 16, 0, 0)

#define WAITV(n) asm volatile("s_waitcnt vmcnt(" #n ")" ::: "memory")
#define LGKM0()  asm volatile("s_waitcnt lgkmcnt(0)" ::: "memory")
#define BAR()    __builtin_amdgcn_s_barrier()
#define SCHEDB() __builtin_amdgcn_sched_barrier(0)

__device__ __forceinline__ void cvt16(const float* __restrict__ p, bf16* __restrict__ q) {
    f32x4 a = *(const f32x4*)p;
    f32x4 b = *(const f32x4*)(p + 4);
    f32x4 c = *(const f32x4*)(p + 8);
    f32x4 d = *(const f32x4*)(p + 12);
    bf16x8 h0, h1;
#pragma unroll
    for (int j = 0; j < 4; ++j) {
        h0[j] = (bf16)a[j]; h0[4 + j] = (bf16)b[j];
        h1[j] = (bf16)c[j]; h1[4 + j] = (bf16)d[j];
    }
    *(bf16x8*)q = h0;
    *(bf16x8*)(q + 8) = h1;
}

// ---------------- fp32 -> bf16 conversion (single src) ----------------
__global__ __launch_bounds__(256) void cvt_f32_bf16(
    const float* __restrict__ src, bf16* __restrict__ dst, int n16)
{
    int idx = blockIdx.x * 256 + threadIdx.x;
    const int stride = gridDim.x * 256;
    for (int i = idx; i < n16; i += stride)
        cvt16(src + (size_t)i * 16, dst + (size_t)i * 16);
}

// ---------------- fused two-segment conversion (x + w_qkv, one launch) ----------------
__global__ __launch_bounds__(256) void cvt2_f32_bf16(
    const float* __restrict__ s1, bf16* __restrict__ d1, int n1,
    const float* __restrict__ s2, bf16* __restrict__ d2, int n2)
{
    int idx = blockIdx.x * 256 + threadIdx.x;
    const int stride = gridDim.x * 256;
    const int ntot = n1 + n2;
    for (int i = idx; i < ntot; i += stride) {
        if (i < n1) cvt16(s1 + (size_t)i * 16, d1 + (size_t)i * 16);
        else {
            const int j = i - n1;
            cvt16(s2 + (size_t)j * 16, d2 + (size_t)j * 16);
        }
    }
}

// ---- r11-verified single-phase 3-deep GEMM: C[M][N] = A[M][K]*B[N][K]^T + bias ----
// BM=128, BN=256, BK=64, 8 waves (2M x 4N -> per-wave 64x64). Measured: 44% MfmaUtil,
// 0 bank conflicts, 246 MB fetch (locality window). Per K-tile: {16 ds_read_b128 ||
// stage t+2 (6 gloads)} -> 32 MFMA -> WAITV(6) -> bar. 3 LDS bufs x 48KB = 144KB.
// Swizzle (r6 HW-verified): phys 16B-slot s of row r holds chunk s^(r&7).
// Block map (nbx%16==0): 256-block window = 16 bx x 16 by; XCD owns 2 bx x 16 by.
template <int OUT_BF16>
__global__ __launch_bounds__(512, 2) void gemm_sp(
    const bf16* __restrict__ A, const bf16* __restrict__ B,
    const float* __restrict__ bias, void* __restrict__ Cout,
    int K, int ldc, int nbx)
{
    constexpr int ASZ = 128 * 64;
    constexpr int BUF = ASZ + 256 * 64;        // 24576 elems = 48KB
    __shared__ bf16 lds[3 * BUF];

    int bx, by;
    if ((nbx & 15) == 0) {
        const int r = (int)blockIdx.x & 255;
        const int slot = r >> 3;
        bx = ((int)blockIdx.x >> 8) * 16 + (r & 7) * 2 + (slot >> 4);
        by = slot & 15;
    } else {
        const int cpx = gridDim.x >> 3;
        const int swz = ((int)blockIdx.x & 7) * cpx + ((int)blockIdx.x >> 3);
        bx = swz % nbx; by = swz / nbx;
    }
    const int brow = by * 128, bcol = bx * 256;

    const int tid  = threadIdx.x;
    const int wv   = tid >> 6, lane = tid & 63;
    const int lo   = lane & 15, hi = lane >> 4;
    const int wrp  = wv >> 2, wcp = wv & 3;

    const int srow = lane >> 3;
    const int scol = ((lane & 7) ^ (lane >> 3)) * 8;

    f32x4 acc[4][4];
#pragma unroll
    for (int m = 0; m < 4; ++m)
#pragma unroll
        for (int n = 0; n < 4; ++n)
            acc[m][n] = (f32x4){0.f, 0.f, 0.f, 0.f};

    auto STAGE = [&](int t) {
        const int k0 = t * 64;
        bf16* lb = &lds[(t % 3) * BUF];
#pragma unroll
        for (int j = 0; j < 2; ++j) {
            const int c = wv * 2 + j;
            GLOAD_LDS16(A + (size_t)(brow + c * 8 + srow) * K + k0 + scol, lb + c * 512);
        }
#pragma unroll
        for (int j = 0; j < 4; ++j) {
            const int c = wv * 4 + j;
            GLOAD_LDS16(B + (size_t)(bcol + c * 8 + srow) * K + k0 + scol, lb + ASZ + c * 512);
        }
    };

    const int nt = K / 64;
    STAGE(0); STAGE(1);
    WAITV(6); BAR(); SCHEDB();

    for (int t = 0; t < nt; ++t) {
        const bf16* lb = &lds[(t % 3) * BUF];
        bf16x8 af[4][2], bfr[4][2];
#pragma unroll
        for (int m = 0; m < 4; ++m) {
            const int ru = wrp * 64 + m * 16 + lo;
#pragma unroll
            for (int kk = 0; kk < 2; ++kk)
                af[m][kk] = *(const bf16x8*)&lb[ru * 64 + (((kk * 4 + hi) ^ (lo & 7)) * 8)];
        }
#pragma unroll
        for (int n = 0; n < 4; ++n) {
            const int rb = wcp * 64 + n * 16 + lo;
#pragma unroll
            for (int kk = 0; kk < 2; ++kk)
                bfr[n][kk] = *(const bf16x8*)&lb[ASZ + rb * 64 + (((kk * 4 + hi) ^ (lo & 7)) * 8)];
        }

        if (t + 2 < nt) STAGE(t + 2);

        __builtin_amdgcn_s_setprio(1);
#pragma unroll
        for (int m = 0; m < 4; ++m)
#pragma unroll
            for (int n = 0; n < 4; ++n)
#pragma unroll
                for (int kk = 0; kk < 2; ++kk)
                    acc[m][n] = __builtin_amdgcn_mfma_f32_16x16x32_bf16(af[m][kk], bfr[n][kk], acc[m][n], 0, 0, 0);
        __builtin_amdgcn_s_setprio(0);

        if (t + 2 < nt)      WAITV(6);
        else if (t + 1 < nt) WAITV(0);
        if (t + 1 < nt) { BAR(); SCHEDB(); }
    }

#pragma unroll
    for (int m = 0; m < 4; ++m) {
        const int row = brow + wrp * 64 + m * 16 + hi * 4;
#pragma unroll
        for (int n = 0; n < 4; ++n) {
            const int col = bcol + wcp * 64 + n * 16 + lo;
            const float bv = bias[col];
#pragma unroll
            for (int r = 0; r < 4; ++r) {
                const float v = acc[m][n][r] + bv;
                if (OUT_BF16)
                    ((bf16*)Cout)[(size_t)(row + r) * ldc + col] = (bf16)v;
                else
                    ((float*)Cout)[(size_t)(row + r) * ldc + col] = v;
            }
        }
    }
}

// ---- MFMA flash attention + T14 async-STAGE (r17/r19-verified, 425.9 us config) ----
// 512 blocks x 512 thr (8 waves); h = bid&31, qi descending (heavy blocks launch first).
// Staging split: ISSUE(t+1) global loads after barrier A (in flight under tile t's
// compute), LDS writes at top of iter t+1. Raw s_barrier (no vmcnt(0) drain).
__global__ __launch_bounds__(512) void attn_mfma(
    const bf16* __restrict__ qkv, bf16* __restrict__ attn_out)
{
    const int S = 2048, QKV = 12288, D = 4096, HD = 128;
    const int bid = blockIdx.x;
    const int h   = bid & 31;
    const int qi  = 15 - (bid >> 5);
    const int q0  = qi * 128;
    const int tid = threadIdx.x;
    const int w    = tid >> 6, lane = tid & 63;
    const int lo   = lane & 15, hi = lane >> 4;
    const int qbase = q0 + w * 16;

    __shared__ bf16 Ks[64 * 128];
    __shared__ bf16 Vs[128 * 72];
    __shared__ bf16 Ps[8 * 16 * 72];

    const float scale = 0.08838834764831845f;
    const float slope = exp2f(-0.25f * (float)(h + 1));

    bf16x8 qfrag[4];
#pragma unroll
    for (int ds = 0; ds < 4; ++ds)
        qfrag[ds] = *(const bf16x8*)(qkv + (size_t)(qbase + lo) * QKV + h * HD + ds * 32 + hi * 8);

    f32x4 o[8];
#pragma unroll
    for (int dt = 0; dt < 8; ++dt) o[dt] = (f32x4){0.f, 0.f, 0.f, 0.f};
    float mrow[4] = {-1e30f, -1e30f, -1e30f, -1e30f};
    float lrow[4] = {0.f, 0.f, 0.f, 0.f};

    const int krow = tid >> 3;        // K: kv row 0..63
    const int kch  = tid & 7;         // K: 16-elem d-chunk
    const int vp2  = tid & 63;        // V: d-pair (d = 2*vp2)
    const int voct = tid >> 6;        // V: kv octet 0..7

    // T14 prefetch state (+16 VGPR)
    bf16x8 kpre0, kpre1;
    unsigned vpre[8];
    auto ISSUE = [&](int t) {
        const int kv0 = t * 64;
        const bf16* kp = qkv + (size_t)(kv0 + krow) * QKV + D + h * HD + kch * 16;
        kpre0 = *(const bf16x8*)kp;
        kpre1 = *(const bf16x8*)(kp + 8);
        const bf16* vp = qkv + (size_t)(kv0 + voct * 8) * QKV + 2 * D + h * HD + 2 * vp2;
#pragma unroll
        for (int j = 0; j < 8; ++j)
            vpre[j] = *(const unsigned*)(vp + (size_t)j * QKV);
    };

    const int ntile = (q0 + 128) / 64;
    ISSUE(0);
    for (int t = 0; t < ntile; ++t) {
        const int kv0 = t * 64;
        // ---- WRITE staged regs to LDS ----
        {
            const int kb  = krow * 128 + kch * 16;
            const int swzk = (krow & 7) << 3;
            *(bf16x8*)&Ks[kb ^ swzk]       = kpre0;
            *(bf16x8*)&Ks[(kb + 8) ^ swzk] = kpre1;
            bf16x8 r0, r1;
#pragma unroll
            for (int j = 0; j < 8; ++j) {
                unsigned short us0 = (unsigned short)(vpre[j] & 0xffff);
                unsigned short us1 = (unsigned short)(vpre[j] >> 16);
                r0[j] = *(const bf16*)&us0;
                r1[j] = *(const bf16*)&us1;
            }
            *(bf16x8*)&Vs[(2 * vp2) * 72 + voct * 8]     = r0;
            *(bf16x8*)&Vs[(2 * vp2 + 1) * 72 + voct * 8] = r1;
        }
        LGKM0(); BAR(); SCHEDB();            // barrier A: staged tile visible

        if (t + 1 < ntile) ISSUE(t + 1);     // HBM loads in flight under compute

        if (kv0 <= qbase + 15) {
            f32x4 c[4];
#pragma unroll
            for (int j = 0; j < 4; ++j) c[j] = (f32x4){0.f, 0.f, 0.f, 0.f};
            __builtin_amdgcn_s_setprio(1);
#pragma unroll
            for (int ds = 0; ds < 4; ++ds) {
#pragma unroll
                for (int j = 0; j < 4; ++j) {
                    const int r = j * 16 + lo;
                    bf16x8 b = *(const bf16x8*)&Ks[(r * 128 + ds * 32 + hi * 8) ^ ((r & 7) << 3)];
                    c[j] = __builtin_amdgcn_mfma_f32_16x16x32_bf16(qfrag[ds], b, c[j], 0, 0, 0);
                }
            }
            __builtin_amdgcn_s_setprio(0);
#pragma unroll
            for (int r = 0; r < 4; ++r) {
                const int q = qbase + hi * 4 + r;
                float s[4];
#pragma unroll
                for (int j = 0; j < 4; ++j) {
                    const int ki = kv0 + j * 16 + lo;
                    s[j] = c[j][r] * scale + slope * (float)(ki - (S - 1));
                    if (ki > q) s[j] = -1e30f;
                }
                float tm = fmaxf(fmaxf(s[0], s[1]), fmaxf(s[2], s[3]));
                tm = fmaxf(tm, __shfl_xor(tm, 1));
                tm = fmaxf(tm, __shfl_xor(tm, 2));
                tm = fmaxf(tm, __shfl_xor(tm, 4));
                tm = fmaxf(tm, __shfl_xor(tm, 8));
                const float mnew = fmaxf(mrow[r], tm);
                const float cr = __expf(mrow[r] - mnew);
                float p[4], ps = 0.f;
#pragma unroll
                for (int j = 0; j < 4; ++j) { p[j] = __expf(s[j] - mnew); ps += p[j]; }
                ps += __shfl_xor(ps, 1);
                ps += __shfl_xor(ps, 2);
                ps += __shfl_xor(ps, 4);
                ps += __shfl_xor(ps, 8);
                lrow[r] = lrow[r] * cr + ps;
                mrow[r] = mnew;
#pragma unroll
                for (int dt = 0; dt < 8; ++dt) o[dt][r] *= cr;
#pragma unroll
                for (int j = 0; j < 4; ++j)
                    Ps[w * 1152 + (hi * 4 + r) * 72 + j * 16 + lo] = (bf16)p[j];
            }
            bf16x8 pa0 = *(const bf16x8*)&Ps[w * 1152 + lo * 72 + hi * 8];
            bf16x8 pa1 = *(const bf16x8*)&Ps[w * 1152 + lo * 72 + 32 + hi * 8];
            __builtin_amdgcn_s_setprio(1);
#pragma unroll
            for (int dt = 0; dt < 8; ++dt) {
                bf16x8 bv0 = *(const bf16x8*)&Vs[(dt * 16 + lo) * 72 + hi * 8];
                bf16x8 bv1 = *(const bf16x8*)&Vs[(dt * 16 + lo) * 72 + 32 + hi * 8];
                o[dt] = __builtin_amdgcn_mfma_f32_16x16x32_bf16(pa0, bv0, o[dt], 0, 0, 0);
                o[dt] = __builtin_amdgcn_mfma_f32_16x16x32_bf16(pa1, bv1, o[dt], 0, 0, 0);
            }
            __builtin_amdgcn_s_setprio(0);
        }
        SCHEDB(); BAR(); SCHEDB();           // barrier B: all reads done before next WRITE
    }

#pragma unroll
    for (int r = 0; r < 4; ++r) {
        const float inv = 1.0f / lrow[r];
        const int q = qbase + hi * 4 + r;
        bf16* op = attn_out + (size_t)q * D + h * HD;
#pragma unroll
        for (int dt = 0; dt < 8; ++dt)
            op[dt * 16 + lo] = (bf16)(o[dt][r] * inv);
    }
}

extern "C" void kernel_launch(void* const* d_in, const int* in_sizes, int n_in,
                              void* d_out, int out_size, void* d_ws, size_t ws_size,
                              hipStream_t stream) {
    const int S = 2048, D = 4096, QKV = 12288;
    const int NH = 6144;
    const float* x     = (const float*)d_in[0];
    const float* w_qkv = (const float*)d_in[1];
    const float* b_qkv = (const float*)d_in[2];
    const float* w_out = (const float*)d_in[3];
    const float* b_out = (const float*)d_in[4];
    float* out = (float*)d_out;

    char* ws = (char*)d_ws;
    const size_t need_full = (size_t)S * D * 2 + (size_t)QKV * D * 2 + (size_t)S * QKV * 2;

    if (ws_size >= need_full) {
        bf16* xb    = (bf16*)ws;                                    // [2048][4096]
        bf16* attnb = xb;                                           // reuse after xb dead
        bf16* wqb   = (bf16*)(ws + (size_t)S * D * 2);              // [12288][4096]
        bf16* wob   = wqb;                                          // reuse after wqb dead
        bf16* qkvb  = (bf16*)(ws + (size_t)S * D * 2 + (size_t)QKV * D * 2);  // [2048][12288]

        cvt2_f32_bf16<<<3584, 256, 0, stream>>>(x, xb, S * D / 16, w_qkv, wqb, QKV * D / 16);
        gemm_sp<1><<<(QKV / 256) * (S / 128), 512, 0, stream>>>(xb, wqb, b_qkv, qkvb, D, QKV, QKV / 256);
        attn_mfma<<<512, 512, 0, stream>>>(qkvb, attnb);
        cvt_f32_bf16<<<2048, 256, 0, stream>>>(w_out, wob, D * D / 16);
        gemm_sp<0><<<(D / 256) * (S / 128), 512, 0, stream>>>(attnb, wob, b_out, out, D, D, D / 256);
    } else {
        bf16* xb    = (bf16*)ws;
        bf16* attnb = xb;
        bf16* wb    = (bf16*)(ws + (size_t)S * D * 2);              // [6144][4096]
        bf16* wob   = wb;
        bf16* qkvb  = (bf16*)(ws + (size_t)S * D * 2 + (size_t)NH * D * 2);

        cvt2_f32_bf16<<<3584, 256, 0, stream>>>(x, xb, S * D / 16, w_qkv, wb, NH * D / 16);
        gemm_sp<1><<<(NH / 256) * (S / 128), 512, 0, stream>>>(xb, wb, b_qkv, qkvb, D, QKV, NH / 256);
        cvt_f32_bf16<<<2048, 256, 0, stream>>>(w_qkv + (size_t)NH * D, wb, NH * D / 16);
        gemm_sp<1><<<(NH / 256) * (S / 128), 512, 0, stream>>>(xb, wb, b_qkv + NH, qkvb + NH, D, QKV, NH / 256);
        attn_mfma<<<512, 512, 0, stream>>>(qkvb, attnb);
        cvt_f32_bf16<<<2048, 256, 0, stream>>>(w_out, wob, D * D / 16);
        gemm_sp<0><<<(D / 256) * (S / 128), 512, 0, stream>>>(attnb, wob, b_out, out, D, D, D / 256);
    }
}